// Round 7
// baseline (1186.951 us; speedup 1.0000x reference)
//
#include <hip/hip_runtime.h>
#include <hip/hip_bf16.h>
#include <stdint.h>

// CrossStreamAttention: B=32768, D=512, H=8, S=3, DH=64
// R8: (a) pack3 fused into qkv_attn — A-tiles reg-staged from the raw f32
// inputs (load float4 x2, v_cvt_pk_bf16_f32, ds_write_b128; identical LDS
// layout/swizzle), h==0 block of each panel side-writes the stacked bf16 S
// (residual for gemm<RES>) from the same registers; (b) 4x cvtbf -> 1 cvtall
// (weight dsts are contiguous in ws). gemm_bt/gate3/lnorm unchanged from the
// 777.9us-verified R7.

typedef float f32x4 __attribute__((ext_vector_type(4)));
typedef short bf16x8 __attribute__((ext_vector_type(8)));  // 8 bf16 in 4 VGPRs

__device__ __forceinline__ float bf2f(unsigned short h) {
  return __uint_as_float(((unsigned)h) << 16);
}
// native RNE convert (v_cvt_pk_bf16_f32 class)
__device__ __forceinline__ unsigned short f2bf(float f) {
  __hip_bfloat16 h = __float2bfloat16(f);
  return *reinterpret_cast<unsigned short*>(&h);
}
// packed pair: lo in low 16 bits, hi in high 16 bits (one v_cvt_pk_bf16_f32)
__device__ __forceinline__ unsigned pack2bf(float lo, float hi) {
  __hip_bfloat162 h2 = __float22bfloat162_rn(make_float2(lo, hi));
  return *reinterpret_cast<unsigned*>(&h2);
}
__device__ __forceinline__ uint2 f2bf4p(float4 v) {
  return make_uint2(pack2bf(v.x, v.y), pack2bf(v.z, v.w));
}

__device__ __forceinline__ void async_cp16(const void* g, void* lds) {
  __builtin_amdgcn_global_load_lds(
      (const __attribute__((address_space(1))) void*)g,
      (__attribute__((address_space(3))) void*)lds, 16, 0, 0);
}

// ---------------------------------------------------------------- converts
// all four weight tensors in one launch; dst segments are contiguous in ws.
__global__ void __launch_bounds__(256) cvtall(const float4* __restrict__ w_in,
                                              const float4* __restrict__ w_out,
                                              const float4* __restrict__ w1,
                                              const float4* __restrict__ w2,
                                              uint2* __restrict__ dst) {
  int i = blockIdx.x * 256 + threadIdx.x;   // 0..786431
  const float4* s;
  int off;
  if (i < 196608)      { s = w_in;  off = 0; }
  else if (i < 262144) { s = w_out; off = 196608; }
  else if (i < 655360) { s = w1;    off = 262144; }
  else                 { s = w2;    off = 655360; }
  dst[i] = f2bf4p(s[i - off]);
}

// ---------------------------------------------------------------- fused QKV gemm + attention
// grid (8, ny). Logical tile: 96 rows (32 b's) x 192 cols (q|k|v of head h).
// XCD-grouped remap: hw id = y*8+x; xcd = id&7; j = id>>3; h = j&7;
// panel = xcd*(ny/8) + (j>>3)  ->  8 consecutive blocks on one XCD share one
// A-panel (f32 inputs fetched once, L2-served 7x). ny % 8 == 0 required.
// A staging: reg-staged from f32 (prefetch issue after barrier[2], convert +
// ds_write at top of next iter). B staging: global_load_lds as before.
// h==0 blocks side-write stacked bf16 S (the residual input of gemm<RES>).
__global__ void __launch_bounds__(256, 4)
qkv_attn(const float* __restrict__ X0,          // kin  [Bc,512] f32
         const float* __restrict__ X1,          // colr
         const float* __restrict__ X2,          // spi
         const unsigned short* __restrict__ Wi, // [1536,512] bf16
         const float* __restrict__ bin,         // [1536]
         unsigned short* __restrict__ Sout,     // [3Bc,512] bf16 side-product
         unsigned short* __restrict__ AO) {     // [3Bc,512] bf16
  __shared__ unsigned short lds[96 * 200];      // 38400 B; union staging/C
  unsigned short* Abuf = lds;                   // [96][64] during K-loop
  unsigned short* Bbuf = lds + 6144;            // [192][64] during K-loop

  const int t = threadIdx.x;
  const int lane = t & 63;
  const int wave = t >> 6;
  const int wm = wave >> 1, wn = wave & 1;

  const int ny = gridDim.y;
  const int id = blockIdx.y * 8 + blockIdx.x;
  const int xcd = id & 7, j = id >> 3;
  const int h = j & 7;
  const long m0 = (long)(xcd * (ny >> 3) + (j >> 3)) * 96;

  const int trow = t >> 3;                      // 0..31 within a 32-row round
  const int swz = ((t & 7) ^ (trow & 7)) << 3;  // element offset
  // A rows rr = m0 + trow + 32r; m0 % 3 == 0 -> b = m0/3 + rl/3, s = rl%3
  const long b0 = m0 / 3;
  const float* Aptr[3];
  unsigned short* Sptr[3];
#pragma unroll
  for (int r = 0; r < 3; r++) {
    const int rl = trow + 32 * r;
    const int br = rl / 3;
    const int sr = rl - 3 * br;
    const float* X = (sr == 0) ? X0 : (sr == 1) ? X1 : X2;
    Aptr[r] = X + (b0 + br) * 512 + swz;
    Sptr[r] = Sout + (m0 + rl) * 512 + swz;
  }
  const unsigned short* Bg = Wi + ((long)h * 64 + trow) * 512 + swz;
  unsigned short* AsD = Abuf + t * 8;
  unsigned short* BsD = Bbuf + t * 8;

  f32x4 acc[3][6] = {};
  const int arow0 = wm * 48 + (lane & 15);
  const int brow0 = wn * 96 + (lane & 15);

  // prefetch A(k0=0) into f32 regs
  float4 Alo[3], Ahi[3];
#pragma unroll
  for (int r = 0; r < 3; r++) {
    Alo[r] = *(const float4*)(Aptr[r]);
    Ahi[r] = *(const float4*)(Aptr[r] + 4);
  }

  for (int k0 = 0; k0 < 512; k0 += 64) {
    __syncthreads();
    // convert prefetched A, commit to LDS (+ S side-write for h==0 blocks)
#pragma unroll
    for (int r = 0; r < 3; r++) {
      const uint4 uv = make_uint4(
          pack2bf(Alo[r].x, Alo[r].y), pack2bf(Alo[r].z, Alo[r].w),
          pack2bf(Ahi[r].x, Ahi[r].y), pack2bf(Ahi[r].z, Ahi[r].w));
      *(uint4*)(AsD + r * 2048) = uv;
      if (h == 0) *(uint4*)(Sptr[r] + k0) = uv;
    }
#pragma unroll
    for (int r = 0; r < 6; r++)
      async_cp16(Bg + (long)((r >> 1) * 512 + (r & 1) * 32) * 512 + k0, BsD + r * 2048);
    __syncthreads();
    // issue next A loads now — overlap with the MFMA phase below
    if (k0 + 64 < 512) {
#pragma unroll
      for (int r = 0; r < 3; r++) {
        Alo[r] = *(const float4*)(Aptr[r] + k0 + 64);
        Ahi[r] = *(const float4*)(Aptr[r] + k0 + 68);
      }
    }
#pragma unroll
    for (int kk = 0; kk < 2; kk++) {
      const int sc = ((kk * 4 + (lane >> 4)) ^ (lane & 7)) << 3;
      bf16x8 af[3], bfr[6];
#pragma unroll
      for (int mt = 0; mt < 3; mt++)
        af[mt] = *(const bf16x8*)&Abuf[(arow0 + mt * 16) * 64 + sc];
#pragma unroll
      for (int nt = 0; nt < 6; nt++)
        bfr[nt] = *(const bf16x8*)&Bbuf[(brow0 + nt * 16) * 64 + sc];
#pragma unroll
      for (int mt = 0; mt < 3; mt++)
#pragma unroll
        for (int nt = 0; nt < 6; nt++)
          acc[mt][nt] = __builtin_amdgcn_mfma_f32_16x16x32_bf16(
              af[mt], bfr[nt], acc[mt][nt], 0, 0, 0);
    }
  }

  // dump C (+bias) as bf16 into LDS, stride 200 — packed converts
  __syncthreads();
  const int crow0 = wm * 48 + ((lane >> 4) << 2);
  const int ccol0 = wn * 96 + (lane & 15);
#pragma unroll
  for (int nt = 0; nt < 6; nt++) {
    const int col = ccol0 + nt * 16;                 // 0..191
    const float bv = bin[(col >> 6) * 512 + h * 64 + (col & 63)];
#pragma unroll
    for (int mt = 0; mt < 3; mt++) {
      const int rb = (crow0 + mt * 16) * 200 + col;
      const unsigned p01 = pack2bf(acc[mt][nt][0] + bv, acc[mt][nt][1] + bv);
      const unsigned p23 = pack2bf(acc[mt][nt][2] + bv, acc[mt][nt][3] + bv);
      lds[rb]       = (unsigned short)p01;
      lds[rb + 200] = (unsigned short)(p01 >> 16);
      lds[rb + 400] = (unsigned short)p23;
      lds[rb + 600] = (unsigned short)(p23 >> 16);
    }
  }
  __syncthreads();

  // attention: wave handles 8 b's; lane = bi*8 + l8; lane owns d = l8*8..+7
  const int bi = lane >> 3;                          // 0..7 (b within wave's 8)
  const int l8 = lane & 7;
  const int r0 = (wave * 8 + bi) * 3;                // local row of stream 0
  float q[3][8], k[3][8], v[3][8];
#pragma unroll
  for (int s = 0; s < 3; s++) {
    const unsigned short* rowp = &lds[(r0 + s) * 200 + l8 * 8];
    uint4 qu = *(const uint4*)(rowp);
    uint4 ku = *(const uint4*)(rowp + 64);
    uint4 vu = *(const uint4*)(rowp + 128);
    const unsigned* qw = (const unsigned*)&qu;
    const unsigned* kw = (const unsigned*)&ku;
    const unsigned* vw = (const unsigned*)&vu;
#pragma unroll
    for (int jj = 0; jj < 4; jj++) {
      q[s][2 * jj]     = __uint_as_float(qw[jj] << 16);
      q[s][2 * jj + 1] = __uint_as_float(qw[jj] & 0xffff0000u);
      k[s][2 * jj]     = __uint_as_float(kw[jj] << 16);
      k[s][2 * jj + 1] = __uint_as_float(kw[jj] & 0xffff0000u);
      v[s][2 * jj]     = __uint_as_float(vw[jj] << 16);
      v[s][2 * jj + 1] = __uint_as_float(vw[jj] & 0xffff0000u);
    }
  }
  float p[3][3];
#pragma unroll
  for (int s = 0; s < 3; s++)
#pragma unroll
    for (int u = 0; u < 3; u++) {
      float d = 0.f;
#pragma unroll
      for (int e = 0; e < 8; e++) d = fmaf(q[s][e], k[u][e], d);
      p[s][u] = d;
    }
#pragma unroll
  for (int m = 1; m < 8; m <<= 1)
#pragma unroll
    for (int s = 0; s < 3; s++)
#pragma unroll
      for (int u = 0; u < 3; u++) p[s][u] += __shfl_xor(p[s][u], m, 64);

  unsigned short* ob = AO + (m0 + r0) * 512 + h * 64 + l8 * 8;
#pragma unroll
  for (int s = 0; s < 3; s++) {
    float a0 = p[s][0] * 0.125f, a1 = p[s][1] * 0.125f, a2 = p[s][2] * 0.125f;
    float mx = fmaxf(a0, fmaxf(a1, a2));
    float e0 = __expf(a0 - mx), e1 = __expf(a1 - mx), e2 = __expf(a2 - mx);
    float inv = 1.0f / (e0 + e1 + e2);
    unsigned ow[4];
#pragma unroll
    for (int jj = 0; jj < 4; jj++) {
      float lo = (e0 * v[0][2 * jj] + e1 * v[1][2 * jj] + e2 * v[2][2 * jj]) * inv;
      float hi = (e0 * v[0][2 * jj + 1] + e1 * v[1][2 * jj + 1] + e2 * v[2][2 * jj + 1]) * inv;
      ow[jj] = pack2bf(lo, hi);
    }
    *(uint4*)(ob + s * 512) = *(uint4*)ow;
  }
}

// ---------------------------------------------------------------- GEMM
// C[M,N] = A[M,K] @ W[N,K]^T + bias. 128x128 tile, BK=64, 4 waves (2x2),
// each wave 64x64 via 4x4 grid of 16x16x32 bf16 MFMA. XCD-grouped swizzle.
enum { EPI_BF16 = 0, EPI_RES = 1, EPI_SILU = 2, EPI_F32 = 3 };

template <int EPI>
__global__ void __launch_bounds__(256)
gemm_bt(const unsigned short* __restrict__ A,
        const unsigned short* __restrict__ W,
        const float* __restrict__ bias,
        const unsigned short* __restrict__ Res,
        void* __restrict__ Out,
        int K, int N) {
  __shared__ unsigned short As[128 * 64];
  __shared__ unsigned short Bs[128 * 64];
  const int t = threadIdx.x;
  const int lane = t & 63;
  const int wave = t >> 6;
  const int wm = wave >> 1, wn = wave & 1;

  const int nb = gridDim.x;
  const int nblocks = nb * gridDim.y;
  const int id = blockIdx.y * nb + blockIdx.x;
  const int lid = ((nblocks & 7) == 0) ? ((id & 7) * (nblocks >> 3) + (id >> 3)) : id;
  const long bm = (long)(lid / nb) * 128;
  const long bn = (long)(lid % nb) * 128;

  const int srow = t >> 3;
  const int schunk = ((t & 7) ^ (srow & 7)) << 3;  // element offset
  const unsigned short* Ag = A + (bm + srow) * (long)K + schunk;
  const unsigned short* Wg = W + (bn + srow) * (long)K + schunk;
  unsigned short* AsD = As + t * 8;
  unsigned short* BsD = Bs + t * 8;

  f32x4 acc[4][4] = {};
  const int arow0 = wm * 64 + (lane & 15);
  const int brow0 = wn * 64 + (lane & 15);

  for (int k0 = 0; k0 < K; k0 += 64) {
    __syncthreads();
#pragma unroll
    for (int i = 0; i < 4; i++) {
      async_cp16(Ag + (long)(i * 32) * K + k0, AsD + i * 2048);
      async_cp16(Wg + (long)(i * 32) * K + k0, BsD + i * 2048);
    }
    __syncthreads();
#pragma unroll
    for (int kk = 0; kk < 2; kk++) {
      const int sc = ((kk * 4 + (lane >> 4)) ^ (lane & 7)) << 3;
      bf16x8 af[4], bfr[4];
#pragma unroll
      for (int mt = 0; mt < 4; mt++)
        af[mt] = *(const bf16x8*)&As[(arow0 + mt * 16) * 64 + sc];
#pragma unroll
      for (int nt = 0; nt < 4; nt++)
        bfr[nt] = *(const bf16x8*)&Bs[(brow0 + nt * 16) * 64 + sc];
#pragma unroll
      for (int mt = 0; mt < 4; mt++)
#pragma unroll
        for (int nt = 0; nt < 4; nt++)
          acc[mt][nt] = __builtin_amdgcn_mfma_f32_16x16x32_bf16(
              af[mt], bfr[nt], acc[mt][nt], 0, 0, 0);
    }
  }

  // C/D layout: col = lane&15, row = (lane>>4)*4 + r
  const long row0 = bm + wm * 64 + ((lane >> 4) << 2);
  const int col0 = (int)bn + wn * 64 + (lane & 15);
#pragma unroll
  for (int nt = 0; nt < 4; nt++) {
    const int col = col0 + nt * 16;
    const float bv = bias[col];
#pragma unroll
    for (int mt = 0; mt < 4; mt++) {
      const long rbase = row0 + mt * 16;
#pragma unroll
      for (int r = 0; r < 4; r++) {
        float v = acc[mt][nt][r] + bv;
        const long idx = (rbase + r) * (long)N + col;
        if (EPI == EPI_RES) v += bf2f(Res[idx]);
        if (EPI == EPI_SILU) v = v * (1.0f / (1.0f + __expf(-v)));
        if (EPI == EPI_F32)
          ((float*)Out)[idx] = v;
        else
          ((unsigned short*)Out)[idx] = f2bf(v);
      }
    }
  }
}

// ---------------------------------------------------------------- gate
// one wave per batch row, ushort8 loads; in-place safe (each wave reads only
// the elements it writes, all reads precede all writes).
__global__ void __launch_bounds__(256) gate3(const unsigned short* AT,
                                             const float* __restrict__ WG,
                                             const float* __restrict__ BG,
                                             unsigned short* G) {
  int row = blockIdx.x * 4 + (threadIdx.x >> 6);
  int lane = threadIdx.x & 63;
  const unsigned short* rp = AT + (long)row * 1536 + lane * 8;
  float x[3][8];
  float p[3] = {0.f, 0.f, 0.f};
#pragma unroll
  for (int seg = 0; seg < 3; seg++) {
    uint4 u = *(const uint4*)(rp + seg * 512);
    const unsigned* uw = (const unsigned*)&u;
#pragma unroll
    for (int j = 0; j < 4; j++) {
      x[seg][2 * j]     = __uint_as_float(uw[j] << 16);
      x[seg][2 * j + 1] = __uint_as_float(uw[j] & 0xffff0000u);
    }
    const int e0 = seg * 512 + lane * 8;
#pragma unroll
    for (int g = 0; g < 3; g++) {
      const float* wp = WG + g * 1536 + e0;
#pragma unroll
      for (int e = 0; e < 8; e++) p[g] = fmaf(x[seg][e], wp[e], p[g]);
    }
  }
#pragma unroll
  for (int m = 1; m < 64; m <<= 1)
#pragma unroll
    for (int g = 0; g < 3; g++) p[g] += __shfl_xor(p[g], m, 64);
  float g0 = p[0] + BG[0], g1 = p[1] + BG[1], g2 = p[2] + BG[2];
  float mx = fmaxf(g0, fmaxf(g1, g2));
  g0 = __expf(g0 - mx); g1 = __expf(g1 - mx); g2 = __expf(g2 - mx);
  float inv = 1.0f / (g0 + g1 + g2);
  float gs[3] = {g0 * inv, g1 * inv, g2 * inv};
  unsigned short* op = G + (long)row * 1536 + lane * 8;
#pragma unroll
  for (int seg = 0; seg < 3; seg++) {
    unsigned ow[4];
#pragma unroll
    for (int j = 0; j < 4; j++)
      ow[j] = pack2bf(x[seg][2 * j] * gs[seg], x[seg][2 * j + 1] * gs[seg]);
    *(uint4*)(op + seg * 512) = *(uint4*)ow;
  }
}

// ---------------------------------------------------------------- layernorm
// one wave per row of 512 f32
__global__ void __launch_bounds__(256) lnorm(const float* __restrict__ F,
                                             const float* __restrict__ gamma,
                                             const float* __restrict__ beta,
                                             float* __restrict__ out) {
  int row = blockIdx.x * 4 + (threadIdx.x >> 6);
  int lane = threadIdx.x & 63;
  const float4* fr = (const float4*)(F + (long)row * 512);
  float4 a = fr[lane], c = fr[lane + 64];
  float s = a.x + a.y + a.z + a.w + c.x + c.y + c.z + c.w;
  float ss = a.x * a.x + a.y * a.y + a.z * a.z + a.w * a.w +
             c.x * c.x + c.y * c.y + c.z * c.z + c.w * c.w;
#pragma unroll
  for (int m = 1; m < 64; m <<= 1) {
    s += __shfl_xor(s, m, 64);
    ss += __shfl_xor(ss, m, 64);
  }
  float mean = s * (1.0f / 512.0f);
  float var = ss * (1.0f / 512.0f) - mean * mean;
  float rstd = rsqrtf(var + 1e-5f);
  const float4* g4 = (const float4*)gamma;
  const float4* b4 = (const float4*)beta;
  float4 g0 = g4[lane], g1 = g4[lane + 64], be0 = b4[lane], be1 = b4[lane + 64];
  float4 o0, o1;
  o0.x = (a.x - mean) * rstd * g0.x + be0.x;
  o0.y = (a.y - mean) * rstd * g0.y + be0.y;
  o0.z = (a.z - mean) * rstd * g0.z + be0.z;
  o0.w = (a.w - mean) * rstd * g0.w + be0.w;
  o1.x = (c.x - mean) * rstd * g1.x + be1.x;
  o1.y = (c.y - mean) * rstd * g1.y + be1.y;
  o1.z = (c.z - mean) * rstd * g1.z + be1.z;
  o1.w = (c.w - mean) * rstd * g1.w + be1.w;
  float4* orow = (float4*)(out + (long)row * 512);
  orow[lane] = o0;
  orow[lane + 64] = o1;
}

// ---------------------------------------------------------------- launch
extern "C" void kernel_launch(void* const* d_in, const int* in_sizes, int n_in,
                              void* d_out, int out_size, void* d_ws, size_t ws_size,
                              hipStream_t stream) {
  const float* kin    = (const float*)d_in[0];
  const float* colr   = (const float*)d_in[1];
  const float* spi    = (const float*)d_in[2];
  const float* w_in   = (const float*)d_in[3];
  const float* b_in   = (const float*)d_in[4];
  const float* w_out  = (const float*)d_in[5];
  const float* b_out  = (const float*)d_in[6];
  const float* w_gate = (const float*)d_in[7];
  const float* b_gate = (const float*)d_in[8];
  const float* w1     = (const float*)d_in[9];
  const float* b1     = (const float*)d_in[10];
  const float* w2     = (const float*)d_in[11];
  const float* b2     = (const float*)d_in[12];
  const float* gamma  = (const float*)d_in[13];
  const float* beta   = (const float*)d_in[14];
  float* out = (float*)d_out;

  // scratch: weights 6,291,456 + S/AO/AT = 9216*Bc (gate in-place, F aliases S)
  long Bc = 32768;
  while (Bc > 1024 && (size_t)(6291456 + 9216 * Bc) > ws_size) Bc >>= 1;
  const int nch = (int)(32768 / Bc);

  char* ws = (char*)d_ws;
  unsigned short* Wic = (unsigned short*)(ws);              // w_in  1536x512
  unsigned short* Woc = (unsigned short*)(ws + 1572864);    // w_out 512x512
  unsigned short* W1c = (unsigned short*)(ws + 2097152);    // w1    1024x1536
  unsigned short* W2c = (unsigned short*)(ws + 5242880);    // w2    512x1024
  char* Sb  = ws + 6291456;                                 // S  [3Bc,512] bf16
  char* AOb = Sb + 3072 * Bc;                               // AO [3Bc,512] bf16
  char* ATb = AOb + 3072 * Bc;                              // AT [3Bc,512] bf16

  cvtall<<<3072, 256, 0, stream>>>((const float4*)w_in, (const float4*)w_out,
                                   (const float4*)w1, (const float4*)w2,
                                   (uint2*)ws);

  for (int c = 0; c < nch; c++) {
    const long boff = (long)c * Bc;
    unsigned short* S_c  = (unsigned short*)Sb;
    unsigned short* AO_c = (unsigned short*)AOb;
    unsigned short* AT_c = (unsigned short*)ATb;
    unsigned short* G_c  = AT_c;                   // gate in-place
    unsigned short* H_c  = (unsigned short*)AOb;   // [Bc,1024], AO dead after proj
    float*          F_c  = (float*)Sb;             // [Bc,512] f32, S dead after proj

    // fused pack + qkv-gemm + attention: f32 inputs -> AO (+ S side-product)
    qkv_attn<<<dim3(8, (int)(Bc / 32)), 256, 0, stream>>>(
        kin + boff * 512, colr + boff * 512, spi + boff * 512,
        Wic, b_in, S_c, AO_c);
    // attn_out = S + AO @ w_out^T + b_out   M=3Bc N=512 K=512
    gemm_bt<EPI_RES><<<dim3(4, (int)(3 * Bc / 128)), 256, 0, stream>>>(
        AO_c, Woc, b_out, S_c, AT_c, 512, 512);
    gate3<<<(int)(Bc / 4), 256, 0, stream>>>(AT_c, w_gate, b_gate, G_c);
    // h = silu(G @ w1^T + b1)           M=Bc N=1024 K=1536
    gemm_bt<EPI_SILU><<<dim3(8, (int)(Bc / 128)), 256, 0, stream>>>(
        G_c, W1c, b1, nullptr, H_c, 1536, 1024);
    // fused = h @ w2^T + b2 (f32)       M=Bc N=512 K=1024
    gemm_bt<EPI_F32><<<dim3(4, (int)(Bc / 128)), 256, 0, stream>>>(
        H_c, W2c, b2, nullptr, F_c, 1024, 512);
    lnorm<<<(int)(Bc / 4), 256, 0, stream>>>(F_c, gamma, beta, out + boff * 512);
  }
}

// Round 8
// 768.493 us; speedup vs baseline: 1.5445x; 1.5445x over previous
//
#include <hip/hip_runtime.h>
#include <hip/hip_bf16.h>
#include <stdint.h>

// CrossStreamAttention: B=32768, D=512, H=8, S=3, DH=64
// R9: R8 with the qkv_attn __launch_bounds__(256,4) -> (256) revert.
// R8 post-mortem: the min-occupancy declaration capped the UNIFIED gfx950
// VGPR+AGPR file at 128/wave (reported 64 arch VGPR), forcing ~550 MB of
// scratch spill traffic per dispatch (WRITE_SIZE 737 MB vs 190 expected,
// qkv 355us, MfmaUtil 8.9%). LDS (38400 B) already limits occupancy to 4
// blocks/CU, so the bound bought nothing. Everything else identical to R8:
// pack3 fused into qkv_attn (A reg-staged from f32, S side-written by h==0
// blocks), cvtall single weight-convert kernel, R7-verified gemm_bt/gate3/
// lnorm.

typedef float f32x4 __attribute__((ext_vector_type(4)));
typedef short bf16x8 __attribute__((ext_vector_type(8)));  // 8 bf16 in 4 VGPRs

__device__ __forceinline__ float bf2f(unsigned short h) {
  return __uint_as_float(((unsigned)h) << 16);
}
// native RNE convert (v_cvt_pk_bf16_f32 class)
__device__ __forceinline__ unsigned short f2bf(float f) {
  __hip_bfloat16 h = __float2bfloat16(f);
  return *reinterpret_cast<unsigned short*>(&h);
}
// packed pair: lo in low 16 bits, hi in high 16 bits (one v_cvt_pk_bf16_f32)
__device__ __forceinline__ unsigned pack2bf(float lo, float hi) {
  __hip_bfloat162 h2 = __float22bfloat162_rn(make_float2(lo, hi));
  return *reinterpret_cast<unsigned*>(&h2);
}
__device__ __forceinline__ uint2 f2bf4p(float4 v) {
  return make_uint2(pack2bf(v.x, v.y), pack2bf(v.z, v.w));
}

__device__ __forceinline__ void async_cp16(const void* g, void* lds) {
  __builtin_amdgcn_global_load_lds(
      (const __attribute__((address_space(1))) void*)g,
      (__attribute__((address_space(3))) void*)lds, 16, 0, 0);
}

// ---------------------------------------------------------------- converts
// all four weight tensors in one launch; dst segments are contiguous in ws.
__global__ void __launch_bounds__(256) cvtall(const float4* __restrict__ w_in,
                                              const float4* __restrict__ w_out,
                                              const float4* __restrict__ w1,
                                              const float4* __restrict__ w2,
                                              uint2* __restrict__ dst) {
  int i = blockIdx.x * 256 + threadIdx.x;   // 0..786431
  const float4* s;
  int off;
  if (i < 196608)      { s = w_in;  off = 0; }
  else if (i < 262144) { s = w_out; off = 196608; }
  else if (i < 655360) { s = w1;    off = 262144; }
  else                 { s = w2;    off = 655360; }
  dst[i] = f2bf4p(s[i - off]);
}

// ---------------------------------------------------------------- fused QKV gemm + attention
// grid (8, ny). Logical tile: 96 rows (32 b's) x 192 cols (q|k|v of head h).
// XCD-grouped remap: hw id = y*8+x; xcd = id&7; j = id>>3; h = j&7;
// panel = xcd*(ny/8) + (j>>3)  ->  8 consecutive blocks on one XCD share one
// A-panel (f32 inputs fetched once, L2-served 7x). ny % 8 == 0 required.
// A staging: reg-staged from f32 (prefetch issue after barrier[2], convert +
// ds_write at top of next iter). B staging: global_load_lds as before.
// h==0 blocks side-write stacked bf16 S (the residual input of gemm<RES>).
__global__ void __launch_bounds__(256)
qkv_attn(const float* __restrict__ X0,          // kin  [Bc,512] f32
         const float* __restrict__ X1,          // colr
         const float* __restrict__ X2,          // spi
         const unsigned short* __restrict__ Wi, // [1536,512] bf16
         const float* __restrict__ bin,         // [1536]
         unsigned short* __restrict__ Sout,     // [3Bc,512] bf16 side-product
         unsigned short* __restrict__ AO) {     // [3Bc,512] bf16
  __shared__ unsigned short lds[96 * 200];      // 38400 B; union staging/C
  unsigned short* Abuf = lds;                   // [96][64] during K-loop
  unsigned short* Bbuf = lds + 6144;            // [192][64] during K-loop

  const int t = threadIdx.x;
  const int lane = t & 63;
  const int wave = t >> 6;
  const int wm = wave >> 1, wn = wave & 1;

  const int ny = gridDim.y;
  const int id = blockIdx.y * 8 + blockIdx.x;
  const int xcd = id & 7, j = id >> 3;
  const int h = j & 7;
  const long m0 = (long)(xcd * (ny >> 3) + (j >> 3)) * 96;

  const int trow = t >> 3;                      // 0..31 within a 32-row round
  const int swz = ((t & 7) ^ (trow & 7)) << 3;  // element offset
  // A rows rr = m0 + trow + 32r; m0 % 3 == 0 -> b = m0/3 + rl/3, s = rl%3
  const long b0 = m0 / 3;
  const float* Aptr[3];
  unsigned short* Sptr[3];
#pragma unroll
  for (int r = 0; r < 3; r++) {
    const int rl = trow + 32 * r;
    const int br = rl / 3;
    const int sr = rl - 3 * br;
    const float* X = (sr == 0) ? X0 : (sr == 1) ? X1 : X2;
    Aptr[r] = X + (b0 + br) * 512 + swz;
    Sptr[r] = Sout + (m0 + rl) * 512 + swz;
  }
  const unsigned short* Bg = Wi + ((long)h * 64 + trow) * 512 + swz;
  unsigned short* AsD = Abuf + t * 8;
  unsigned short* BsD = Bbuf + t * 8;

  f32x4 acc[3][6] = {};
  const int arow0 = wm * 48 + (lane & 15);
  const int brow0 = wn * 96 + (lane & 15);

  // prefetch A(k0=0) into f32 regs
  float4 Alo[3], Ahi[3];
#pragma unroll
  for (int r = 0; r < 3; r++) {
    Alo[r] = *(const float4*)(Aptr[r]);
    Ahi[r] = *(const float4*)(Aptr[r] + 4);
  }

  for (int k0 = 0; k0 < 512; k0 += 64) {
    __syncthreads();
    // convert prefetched A, commit to LDS (+ S side-write for h==0 blocks)
#pragma unroll
    for (int r = 0; r < 3; r++) {
      const uint4 uv = make_uint4(
          pack2bf(Alo[r].x, Alo[r].y), pack2bf(Alo[r].z, Alo[r].w),
          pack2bf(Ahi[r].x, Ahi[r].y), pack2bf(Ahi[r].z, Ahi[r].w));
      *(uint4*)(AsD + r * 2048) = uv;
      if (h == 0) *(uint4*)(Sptr[r] + k0) = uv;
    }
#pragma unroll
    for (int r = 0; r < 6; r++)
      async_cp16(Bg + (long)((r >> 1) * 512 + (r & 1) * 32) * 512 + k0, BsD + r * 2048);
    __syncthreads();
    // issue next A loads now — overlap with the MFMA phase below
    if (k0 + 64 < 512) {
#pragma unroll
      for (int r = 0; r < 3; r++) {
        Alo[r] = *(const float4*)(Aptr[r] + k0 + 64);
        Ahi[r] = *(const float4*)(Aptr[r] + k0 + 68);
      }
    }
#pragma unroll
    for (int kk = 0; kk < 2; kk++) {
      const int sc = ((kk * 4 + (lane >> 4)) ^ (lane & 7)) << 3;
      bf16x8 af[3], bfr[6];
#pragma unroll
      for (int mt = 0; mt < 3; mt++)
        af[mt] = *(const bf16x8*)&Abuf[(arow0 + mt * 16) * 64 + sc];
#pragma unroll
      for (int nt = 0; nt < 6; nt++)
        bfr[nt] = *(const bf16x8*)&Bbuf[(brow0 + nt * 16) * 64 + sc];
#pragma unroll
      for (int mt = 0; mt < 3; mt++)
#pragma unroll
        for (int nt = 0; nt < 6; nt++)
          acc[mt][nt] = __builtin_amdgcn_mfma_f32_16x16x32_bf16(
              af[mt], bfr[nt], acc[mt][nt], 0, 0, 0);
    }
  }

  // dump C (+bias) as bf16 into LDS, stride 200 — packed converts
  __syncthreads();
  const int crow0 = wm * 48 + ((lane >> 4) << 2);
  const int ccol0 = wn * 96 + (lane & 15);
#pragma unroll
  for (int nt = 0; nt < 6; nt++) {
    const int col = ccol0 + nt * 16;                 // 0..191
    const float bv = bin[(col >> 6) * 512 + h * 64 + (col & 63)];
#pragma unroll
    for (int mt = 0; mt < 3; mt++) {
      const int rb = (crow0 + mt * 16) * 200 + col;
      const unsigned p01 = pack2bf(acc[mt][nt][0] + bv, acc[mt][nt][1] + bv);
      const unsigned p23 = pack2bf(acc[mt][nt][2] + bv, acc[mt][nt][3] + bv);
      lds[rb]       = (unsigned short)p01;
      lds[rb + 200] = (unsigned short)(p01 >> 16);
      lds[rb + 400] = (unsigned short)p23;
      lds[rb + 600] = (unsigned short)(p23 >> 16);
    }
  }
  __syncthreads();

  // attention: wave handles 8 b's; lane = bi*8 + l8; lane owns d = l8*8..+7
  const int bi = lane >> 3;                          // 0..7 (b within wave's 8)
  const int l8 = lane & 7;
  const int r0 = (wave * 8 + bi) * 3;                // local row of stream 0
  float q[3][8], k[3][8], v[3][8];
#pragma unroll
  for (int s = 0; s < 3; s++) {
    const unsigned short* rowp = &lds[(r0 + s) * 200 + l8 * 8];
    uint4 qu = *(const uint4*)(rowp);
    uint4 ku = *(const uint4*)(rowp + 64);
    uint4 vu = *(const uint4*)(rowp + 128);
    const unsigned* qw = (const unsigned*)&qu;
    const unsigned* kw = (const unsigned*)&ku;
    const unsigned* vw = (const unsigned*)&vu;
#pragma unroll
    for (int jj = 0; jj < 4; jj++) {
      q[s][2 * jj]     = __uint_as_float(qw[jj] << 16);
      q[s][2 * jj + 1] = __uint_as_float(qw[jj] & 0xffff0000u);
      k[s][2 * jj]     = __uint_as_float(kw[jj] << 16);
      k[s][2 * jj + 1] = __uint_as_float(kw[jj] & 0xffff0000u);
      v[s][2 * jj]     = __uint_as_float(vw[jj] << 16);
      v[s][2 * jj + 1] = __uint_as_float(vw[jj] & 0xffff0000u);
    }
  }
  float p[3][3];
#pragma unroll
  for (int s = 0; s < 3; s++)
#pragma unroll
    for (int u = 0; u < 3; u++) {
      float d = 0.f;
#pragma unroll
      for (int e = 0; e < 8; e++) d = fmaf(q[s][e], k[u][e], d);
      p[s][u] = d;
    }
#pragma unroll
  for (int m = 1; m < 8; m <<= 1)
#pragma unroll
    for (int s = 0; s < 3; s++)
#pragma unroll
      for (int u = 0; u < 3; u++) p[s][u] += __shfl_xor(p[s][u], m, 64);

  unsigned short* ob = AO + (m0 + r0) * 512 + h * 64 + l8 * 8;
#pragma unroll
  for (int s = 0; s < 3; s++) {
    float a0 = p[s][0] * 0.125f, a1 = p[s][1] * 0.125f, a2 = p[s][2] * 0.125f;
    float mx = fmaxf(a0, fmaxf(a1, a2));
    float e0 = __expf(a0 - mx), e1 = __expf(a1 - mx), e2 = __expf(a2 - mx);
    float inv = 1.0f / (e0 + e1 + e2);
    unsigned ow[4];
#pragma unroll
    for (int jj = 0; jj < 4; jj++) {
      float lo = (e0 * v[0][2 * jj] + e1 * v[1][2 * jj] + e2 * v[2][2 * jj]) * inv;
      float hi = (e0 * v[0][2 * jj + 1] + e1 * v[1][2 * jj + 1] + e2 * v[2][2 * jj + 1]) * inv;
      ow[jj] = pack2bf(lo, hi);
    }
    *(uint4*)(ob + s * 512) = *(uint4*)ow;
  }
}

// ---------------------------------------------------------------- GEMM
// C[M,N] = A[M,K] @ W[N,K]^T + bias. 128x128 tile, BK=64, 4 waves (2x2),
// each wave 64x64 via 4x4 grid of 16x16x32 bf16 MFMA. XCD-grouped swizzle.
enum { EPI_BF16 = 0, EPI_RES = 1, EPI_SILU = 2, EPI_F32 = 3 };

template <int EPI>
__global__ void __launch_bounds__(256)
gemm_bt(const unsigned short* __restrict__ A,
        const unsigned short* __restrict__ W,
        const float* __restrict__ bias,
        const unsigned short* __restrict__ Res,
        void* __restrict__ Out,
        int K, int N) {
  __shared__ unsigned short As[128 * 64];
  __shared__ unsigned short Bs[128 * 64];
  const int t = threadIdx.x;
  const int lane = t & 63;
  const int wave = t >> 6;
  const int wm = wave >> 1, wn = wave & 1;

  const int nb = gridDim.x;
  const int nblocks = nb * gridDim.y;
  const int id = blockIdx.y * nb + blockIdx.x;
  const int lid = ((nblocks & 7) == 0) ? ((id & 7) * (nblocks >> 3) + (id >> 3)) : id;
  const long bm = (long)(lid / nb) * 128;
  const long bn = (long)(lid % nb) * 128;

  const int srow = t >> 3;
  const int schunk = ((t & 7) ^ (srow & 7)) << 3;  // element offset
  const unsigned short* Ag = A + (bm + srow) * (long)K + schunk;
  const unsigned short* Wg = W + (bn + srow) * (long)K + schunk;
  unsigned short* AsD = As + t * 8;
  unsigned short* BsD = Bs + t * 8;

  f32x4 acc[4][4] = {};
  const int arow0 = wm * 64 + (lane & 15);
  const int brow0 = wn * 64 + (lane & 15);

  for (int k0 = 0; k0 < K; k0 += 64) {
    __syncthreads();
#pragma unroll
    for (int i = 0; i < 4; i++) {
      async_cp16(Ag + (long)(i * 32) * K + k0, AsD + i * 2048);
      async_cp16(Wg + (long)(i * 32) * K + k0, BsD + i * 2048);
    }
    __syncthreads();
#pragma unroll
    for (int kk = 0; kk < 2; kk++) {
      const int sc = ((kk * 4 + (lane >> 4)) ^ (lane & 7)) << 3;
      bf16x8 af[4], bfr[4];
#pragma unroll
      for (int mt = 0; mt < 4; mt++)
        af[mt] = *(const bf16x8*)&As[(arow0 + mt * 16) * 64 + sc];
#pragma unroll
      for (int nt = 0; nt < 4; nt++)
        bfr[nt] = *(const bf16x8*)&Bs[(brow0 + nt * 16) * 64 + sc];
#pragma unroll
      for (int mt = 0; mt < 4; mt++)
#pragma unroll
        for (int nt = 0; nt < 4; nt++)
          acc[mt][nt] = __builtin_amdgcn_mfma_f32_16x16x32_bf16(
              af[mt], bfr[nt], acc[mt][nt], 0, 0, 0);
    }
  }

  // C/D layout: col = lane&15, row = (lane>>4)*4 + r
  const long row0 = bm + wm * 64 + ((lane >> 4) << 2);
  const int col0 = (int)bn + wn * 64 + (lane & 15);
#pragma unroll
  for (int nt = 0; nt < 4; nt++) {
    const int col = col0 + nt * 16;
    const float bv = bias[col];
#pragma unroll
    for (int mt = 0; mt < 4; mt++) {
      const long rbase = row0 + mt * 16;
#pragma unroll
      for (int r = 0; r < 4; r++) {
        float v = acc[mt][nt][r] + bv;
        const long idx = (rbase + r) * (long)N + col;
        if (EPI == EPI_RES) v += bf2f(Res[idx]);
        if (EPI == EPI_SILU) v = v * (1.0f / (1.0f + __expf(-v)));
        if (EPI == EPI_F32)
          ((float*)Out)[idx] = v;
        else
          ((unsigned short*)Out)[idx] = f2bf(v);
      }
    }
  }
}

// ---------------------------------------------------------------- gate
// one wave per batch row, ushort8 loads; in-place safe (each wave reads only
// the elements it writes, all reads precede all writes).
__global__ void __launch_bounds__(256) gate3(const unsigned short* AT,
                                             const float* __restrict__ WG,
                                             const float* __restrict__ BG,
                                             unsigned short* G) {
  int row = blockIdx.x * 4 + (threadIdx.x >> 6);
  int lane = threadIdx.x & 63;
  const unsigned short* rp = AT + (long)row * 1536 + lane * 8;
  float x[3][8];
  float p[3] = {0.f, 0.f, 0.f};
#pragma unroll
  for (int seg = 0; seg < 3; seg++) {
    uint4 u = *(const uint4*)(rp + seg * 512);
    const unsigned* uw = (const unsigned*)&u;
#pragma unroll
    for (int j = 0; j < 4; j++) {
      x[seg][2 * j]     = __uint_as_float(uw[j] << 16);
      x[seg][2 * j + 1] = __uint_as_float(uw[j] & 0xffff0000u);
    }
    const int e0 = seg * 512 + lane * 8;
#pragma unroll
    for (int g = 0; g < 3; g++) {
      const float* wp = WG + g * 1536 + e0;
#pragma unroll
      for (int e = 0; e < 8; e++) p[g] = fmaf(x[seg][e], wp[e], p[g]);
    }
  }
#pragma unroll
  for (int m = 1; m < 64; m <<= 1)
#pragma unroll
    for (int g = 0; g < 3; g++) p[g] += __shfl_xor(p[g], m, 64);
  float g0 = p[0] + BG[0], g1 = p[1] + BG[1], g2 = p[2] + BG[2];
  float mx = fmaxf(g0, fmaxf(g1, g2));
  g0 = __expf(g0 - mx); g1 = __expf(g1 - mx); g2 = __expf(g2 - mx);
  float inv = 1.0f / (g0 + g1 + g2);
  float gs[3] = {g0 * inv, g1 * inv, g2 * inv};
  unsigned short* op = G + (long)row * 1536 + lane * 8;
#pragma unroll
  for (int seg = 0; seg < 3; seg++) {
    unsigned ow[4];
#pragma unroll
    for (int j = 0; j < 4; j++)
      ow[j] = pack2bf(x[seg][2 * j] * gs[seg], x[seg][2 * j + 1] * gs[seg]);
    *(uint4*)(op + seg * 512) = *(uint4*)ow;
  }
}

// ---------------------------------------------------------------- layernorm
// one wave per row of 512 f32
__global__ void __launch_bounds__(256) lnorm(const float* __restrict__ F,
                                             const float* __restrict__ gamma,
                                             const float* __restrict__ beta,
                                             float* __restrict__ out) {
  int row = blockIdx.x * 4 + (threadIdx.x >> 6);
  int lane = threadIdx.x & 63;
  const float4* fr = (const float4*)(F + (long)row * 512);
  float4 a = fr[lane], c = fr[lane + 64];
  float s = a.x + a.y + a.z + a.w + c.x + c.y + c.z + c.w;
  float ss = a.x * a.x + a.y * a.y + a.z * a.z + a.w * a.w +
             c.x * c.x + c.y * c.y + c.z * c.z + c.w * c.w;
#pragma unroll
  for (int m = 1; m < 64; m <<= 1) {
    s += __shfl_xor(s, m, 64);
    ss += __shfl_xor(ss, m, 64);
  }
  float mean = s * (1.0f / 512.0f);
  float var = ss * (1.0f / 512.0f) - mean * mean;
  float rstd = rsqrtf(var + 1e-5f);
  const float4* g4 = (const float4*)gamma;
  const float4* b4 = (const float4*)beta;
  float4 g0 = g4[lane], g1 = g4[lane + 64], be0 = b4[lane], be1 = b4[lane + 64];
  float4 o0, o1;
  o0.x = (a.x - mean) * rstd * g0.x + be0.x;
  o0.y = (a.y - mean) * rstd * g0.y + be0.y;
  o0.z = (a.z - mean) * rstd * g0.z + be0.z;
  o0.w = (a.w - mean) * rstd * g0.w + be0.w;
  o1.x = (c.x - mean) * rstd * g1.x + be1.x;
  o1.y = (c.y - mean) * rstd * g1.y + be1.y;
  o1.z = (c.z - mean) * rstd * g1.z + be1.z;
  o1.w = (c.w - mean) * rstd * g1.w + be1.w;
  float4* orow = (float4*)(out + (long)row * 512);
  orow[lane] = o0;
  orow[lane + 64] = o1;
}

// ---------------------------------------------------------------- launch
extern "C" void kernel_launch(void* const* d_in, const int* in_sizes, int n_in,
                              void* d_out, int out_size, void* d_ws, size_t ws_size,
                              hipStream_t stream) {
  const float* kin    = (const float*)d_in[0];
  const float* colr   = (const float*)d_in[1];
  const float* spi    = (const float*)d_in[2];
  const float* w_in   = (const float*)d_in[3];
  const float* b_in   = (const float*)d_in[4];
  const float* w_out  = (const float*)d_in[5];
  const float* b_out  = (const float*)d_in[6];
  const float* w_gate = (const float*)d_in[7];
  const float* b_gate = (const float*)d_in[8];
  const float* w1     = (const float*)d_in[9];
  const float* b1     = (const float*)d_in[10];
  const float* w2     = (const float*)d_in[11];
  const float* b2     = (const float*)d_in[12];
  const float* gamma  = (const float*)d_in[13];
  const float* beta   = (const float*)d_in[14];
  float* out = (float*)d_out;

  // scratch: weights 6,291,456 + S/AO/AT = 9216*Bc (gate in-place, F aliases S)
  long Bc = 32768;
  while (Bc > 1024 && (size_t)(6291456 + 9216 * Bc) > ws_size) Bc >>= 1;
  const int nch = (int)(32768 / Bc);

  char* ws = (char*)d_ws;
  unsigned short* Wic = (unsigned short*)(ws);              // w_in  1536x512
  unsigned short* Woc = (unsigned short*)(ws + 1572864);    // w_out 512x512
  unsigned short* W1c = (unsigned short*)(ws + 2097152);    // w1    1024x1536
  unsigned short* W2c = (unsigned short*)(ws + 5242880);    // w2    512x1024
  char* Sb  = ws + 6291456;                                 // S  [3Bc,512] bf16
  char* AOb = Sb + 3072 * Bc;                               // AO [3Bc,512] bf16
  char* ATb = AOb + 3072 * Bc;                              // AT [3Bc,512] bf16

  cvtall<<<3072, 256, 0, stream>>>((const float4*)w_in, (const float4*)w_out,
                                   (const float4*)w1, (const float4*)w2,
                                   (uint2*)ws);

  for (int c = 0; c < nch; c++) {
    const long boff = (long)c * Bc;
    unsigned short* S_c  = (unsigned short*)Sb;
    unsigned short* AO_c = (unsigned short*)AOb;
    unsigned short* AT_c = (unsigned short*)ATb;
    unsigned short* G_c  = AT_c;                   // gate in-place
    unsigned short* H_c  = (unsigned short*)AOb;   // [Bc,1024], AO dead after proj
    float*          F_c  = (float*)Sb;             // [Bc,512] f32, S dead after proj

    // fused pack + qkv-gemm + attention: f32 inputs -> AO (+ S side-product)
    qkv_attn<<<dim3(8, (int)(Bc / 32)), 256, 0, stream>>>(
        kin + boff * 512, colr + boff * 512, spi + boff * 512,
        Wic, b_in, S_c, AO_c);
    // attn_out = S + AO @ w_out^T + b_out   M=3Bc N=512 K=512
    gemm_bt<EPI_RES><<<dim3(4, (int)(3 * Bc / 128)), 256, 0, stream>>>(
        AO_c, Woc, b_out, S_c, AT_c, 512, 512);
    gate3<<<(int)(Bc / 4), 256, 0, stream>>>(AT_c, w_gate, b_gate, G_c);
    // h = silu(G @ w1^T + b1)           M=Bc N=1024 K=1536
    gemm_bt<EPI_SILU><<<dim3(8, (int)(Bc / 128)), 256, 0, stream>>>(
        G_c, W1c, b1, nullptr, H_c, 1536, 1024);
    // fused = h @ w2^T + b2 (f32)       M=Bc N=512 K=1024
    gemm_bt<EPI_F32><<<dim3(4, (int)(Bc / 128)), 256, 0, stream>>>(
        H_c, W2c, b2, nullptr, F_c, 1024, 512);
    lnorm<<<(int)(Bc / 4), 256, 0, stream>>>(F_c, gamma, beta, out + boff * 512);
  }
}